// Round 5
// baseline (363.653 us; speedup 1.0000x reference)
//
#include <hip/hip_runtime.h>

// SoftEmbeddedDecisionRules: balanced binary hierarchy over C=1024 classes.
// out[b,c] = prod over 10 levels of 2-way softmax prob of c's branch;
// 2-way softmax == sigmoid(diff of child means).
//
// R5: minimize VALU issue (R4 measured ~38us of VALU at 80us total).
// Each lane owns 16 CONTIGUOUS classes -> bottom 4 levels (15 sigmoids) are
// lane-local and unique across lanes; top 6 levels via 6-step __shfl_xor
// butterfly (6 sigmoids). 21 sigmoids/lane vs R4's 39, 6 shfls vs 24.
// Manual next-row prefetch overlaps streaming with the compute chain.

#define C 1024

typedef float f4 __attribute__((ext_vector_type(4)));

__device__ __forceinline__ float sigd(float d) {  // 1/(1+exp(d))
    return 1.0f / (1.0f + __expf(d));
}

__global__ __launch_bounds__(256, 4) void hier_softmax_kernel(
    const float* __restrict__ in, float* __restrict__ out, int B) {
    const int lane = threadIdx.x & 63;
    const int waveId = (blockIdx.x * blockDim.x + threadIdx.x) >> 6;
    const int nWaves = (gridDim.x * blockDim.x) >> 6;

    int row = waveId;
    if (row >= B) return;

    // lane's 16 classes: [lane*16, lane*16+16) -> 4 consecutive f4 loads
    f4 v[4];
    {
        const f4* rowp = (const f4*)(in + (size_t)row * C);
#pragma unroll
        for (int j = 0; j < 4; ++j) v[j] = rowp[lane * 4 + j];
    }

    while (row < B) {
        const int nrow = row + nWaves;
        f4 vn[4];
        if (nrow < B) {  // wave-uniform branch; prefetch next row
            const f4* np = (const f4*)(in + (size_t)nrow * C);
#pragma unroll
            for (int j = 0; j < 4; ++j) vn[j] = np[lane * 4 + j];
        }

        float x[16];
#pragma unroll
        for (int j = 0; j < 4; ++j) {
            x[4 * j + 0] = v[j].x; x[4 * j + 1] = v[j].y;
            x[4 * j + 2] = v[j].z; x[4 * j + 3] = v[j].w;
        }

        // lane-local bottom 4 levels (all unique nodes)
        float p1[8], s2[8];
#pragma unroll
        for (int k = 0; k < 8; ++k) {
            p1[k] = sigd(x[2 * k + 1] - x[2 * k]);  // p(left) of pair k
            s2[k] = x[2 * k] + x[2 * k + 1];
        }
        float p2[4], s4[4];
#pragma unroll
        for (int k = 0; k < 4; ++k) {
            p2[k] = sigd((s2[2 * k + 1] - s2[2 * k]) * 0.5f);
            s4[k] = s2[2 * k] + s2[2 * k + 1];
        }
        float p4[2], s8[2];
#pragma unroll
        for (int k = 0; k < 2; ++k) {
            p4[k] = sigd((s4[2 * k + 1] - s4[2 * k]) * 0.25f);
            s8[k] = s4[2 * k] + s4[2 * k + 1];
        }
        const float p8 = sigd((s8[1] - s8[0]) * 0.125f);
        float S = s8[0] + s8[1];  // lane's seg-16 block sum

        // top 6 levels: butterfly over 64 lane-blocks
        float common = 1.0f;
        float inv = 0.0625f;  // 1/16 = 1/child_seg at first merge
#pragma unroll
        for (int m = 1; m <= 32; m <<= 1) {
            const float sib = __shfl_xor(S, m, 64);
            common *= sigd((sib - S) * inv);  // p(own branch)
            S += sib;
            inv *= 0.5f;
        }

        // downsweep expansion: c*(1-p) == c - c*p
        float c8[2], c4[4], c2[8];
        c8[0] = common * p8;
        c8[1] = common - c8[0];
#pragma unroll
        for (int k = 0; k < 2; ++k) {
            c4[2 * k] = c8[k] * p4[k];
            c4[2 * k + 1] = c8[k] - c4[2 * k];
        }
#pragma unroll
        for (int k = 0; k < 4; ++k) {
            c2[2 * k] = c4[k] * p2[k];
            c2[2 * k + 1] = c4[k] - c2[2 * k];
        }

        f4* orow = (f4*)(out + (size_t)row * C);
#pragma unroll
        for (int j = 0; j < 4; ++j) {
            const int k0 = 2 * j, k1 = 2 * j + 1;
            f4 o;
            o.x = c2[k0] * p1[k0];
            o.y = c2[k0] - o.x;
            o.z = c2[k1] * p1[k1];
            o.w = c2[k1] - o.z;
            __builtin_nontemporal_store(o, orow + lane * 4 + j);
        }

        row = nrow;
#pragma unroll
        for (int j = 0; j < 4; ++j) v[j] = vn[j];
    }
}

extern "C" void kernel_launch(void* const* d_in, const int* in_sizes, int n_in,
                              void* d_out, int out_size, void* d_ws, size_t ws_size,
                              hipStream_t stream) {
    const float* in = (const float*)d_in[0];
    float* out = (float*)d_out;
    const int B = in_sizes[0] / C;  // 32768
    hier_softmax_kernel<<<2048, 256, 0, stream>>>(in, out, B);
}